// Round 7
// baseline (430.321 us; speedup 1.0000x reference)
//
#include <hip/hip_runtime.h>
#include <hip/hip_bf16.h>

typedef __attribute__((ext_vector_type(8))) short short8;
typedef __attribute__((ext_vector_type(4))) float floatx4;
typedef __attribute__((ext_vector_type(4))) unsigned short ushort4v;
typedef __attribute__((ext_vector_type(2))) unsigned int uint2v;
typedef __attribute__((ext_vector_type(4))) unsigned int uint4v;

#define NN 10000
#define E0 160000
#define ETOT (E0 + NN)
#define IN_DIM 512
#define HID1 1024   /* HEADS*HID = 8*128 */
#define EMB 256
#define MPAD 10112  /* 79 * 128 */
#define NX (NN * IN_DIM)
#define NW1 (IN_DIM * HID1)
#define NW2 (HID1 * EMB)
#define DETB 625    /* E0/256 detect blocks in probe_kernel */
#define EPAD 170240 /* ETOT padded to 256 */

__device__ __forceinline__ float bf2f(unsigned short u) {
    unsigned v = ((unsigned)u) << 16;
    float f;
    __builtin_memcpy(&f, &v, 4);
    return f;
}
__device__ __forceinline__ float bflo(unsigned v) {
    unsigned x = v << 16;
    float f; __builtin_memcpy(&f, &x, 4);
    return f;
}
__device__ __forceinline__ float bfhi(unsigned v) {
    unsigned x = v & 0xffff0000u;
    float f; __builtin_memcpy(&f, &x, 4);
    return f;
}
__device__ __forceinline__ unsigned short f2bf(float f) {
    unsigned u;
    __builtin_memcpy(&u, &f, 4);
    unsigned lsb = (u >> 16) & 1;
    u += 0x7fff + lsb;           // round-to-nearest-even
    return (unsigned short)(u >> 16);
}
__device__ __forceinline__ unsigned packbf(float lo, float hi) {
    return (unsigned)f2bf(lo) | ((unsigned)f2bf(hi) << 16);
}
__device__ __forceinline__ float loadf(const void* p, size_t i, int isf32) {
    if (isf32) return ((const float*)p)[i];
    return bf2f(((const unsigned short*)p)[i]);
}
__device__ __forceinline__ float lrelu(float e) { return e > 0.f ? e : 0.2f * e; }

// ---------------- zero fill ----------------
__global__ void zero_kernel(int* p, int n) {
    int i = blockIdx.x * 256 + threadIdx.x;
    if (i < n) p[i] = 0;
}

// ---------------- fused probe: edge dtype (blocks 0..DETB-1) + float dtype (block DETB) ----------------
__global__ __launch_bounds__(256) void probe_kernel(const int* ei32, const unsigned* xw,
                                                    int* eflag, int* isf32) {
    int t = threadIdx.x;
    if (blockIdx.x < DETB) {
        int i = blockIdx.x * 256 + t;
        int v = 0;
        int idx = 2 * i + 1;
        if (idx < 2 * E0) v = ei32[idx];
        unsigned long long any = __ballot(v != 0);
        if (any && (t & 63) == 0) atomicOr(eflag, 1);
    } else {
        __shared__ int cnt[256];
        int c = 0;
        #pragma unroll
        for (int j = 0; j < 16; ++j) {
            unsigned w = xw[t * 16 + j];
            int ex = (w >> 7) & 0xFF;
            if (ex >= 110 && ex <= 135) c++;
        }
        cnt[t] = c;
        __syncthreads();
        for (int off = 128; off > 0; off >>= 1) {
            if (t < off) cnt[t] += cnt[t + off];
            __syncthreads();
        }
        if (t == 0) *isf32 = (cnt[0] < 2048) ? 1 : 0;
    }
}

__device__ __forceinline__ int load_edge(const void* ei, long long idx, int m32) {
    if (m32) return ((const int*)ei)[idx];
    return (int)(((const long long*)ei)[idx]);
}

// ---------------- CSR build ----------------
__global__ void count_kernel(const void* ei, const int* flag, int* counts) {
    int e = blockIdx.x * 256 + threadIdx.x;
    if (e < E0) {
        int m32 = (*flag != 0);
        int d = load_edge(ei, (long long)E0 + e, m32);
        if (d >= 0 && d < NN) atomicAdd(&counts[d], 1);
    }
}

// shfl-based block scan: 1024 threads x 10 values, 2 barriers total.
__global__ __launch_bounds__(1024) void scan_kernel(const int* counts, int* offsets, int* cursor) {
    __shared__ int wsum[16];
    int t = threadIdx.x;
    int lane = t & 63, wv = t >> 6;
    int base = t * 10;
    int local[10];
    int s = 0;
    #pragma unroll
    for (int j = 0; j < 10; ++j) {
        int idx = base + j;
        int v = (idx < NN) ? (counts[idx] + 1) : 0;  // +1 self loop
        local[j] = v; s += v;
    }
    // inclusive wave scan of s
    int v = s;
    #pragma unroll
    for (int d = 1; d < 64; d <<= 1) {
        int o = __shfl_up(v, d, 64);
        if (lane >= d) v += o;
    }
    if (lane == 63) wsum[wv] = v;
    __syncthreads();
    if (t < 16) {
        int w = wsum[t];
        #pragma unroll
        for (int d = 1; d < 16; d <<= 1) {
            int o = __shfl_up(w, d, 16);
            if (t >= d) w += o;
        }
        wsum[t] = w;
    }
    __syncthreads();
    int woff = (wv == 0) ? 0 : wsum[wv - 1];
    int run = woff + v - s;   // exclusive prefix for this thread
    #pragma unroll
    for (int j = 0; j < 10; ++j) {
        int idx = base + j;
        if (idx < NN) { offsets[idx] = run; cursor[idx] = run; run += local[j]; }
    }
    if (t == 1023) offsets[NN] = wsum[15];
}

__global__ void scatter_kernel(const void* ei, const int* flag, int* cursor,
                               int* csr_src, int* csr_dst) {
    int e = blockIdx.x * 256 + threadIdx.x;
    if (e >= ETOT) return;
    int m32 = (*flag != 0);
    int s, d;
    if (e < E0) { s = load_edge(ei, e, m32); d = load_edge(ei, (long long)E0 + e, m32); }
    else { s = d = e - E0; }
    if (s < 0) s = 0; if (s >= NN) s = NN - 1;
    if (d < 0) d = 0; if (d >= NN) d = NN - 1;
    int pos = atomicAdd(&cursor[d], 1);
    if (pos >= 0 && pos < ETOT) { csr_src[pos] = s; csr_dst[pos] = d; }
}

// ---------------- fused fp32->bf16 conversions (x, W1^T, W2^T in one launch) ----------------
__global__ void convall_kernel(const void* x, const void* W1, const void* W2,
                               unsigned short* xb, unsigned short* W1t, unsigned short* W2t,
                               const int* isf32)
{
    int i = blockIdx.x * 256 + threadIdx.x;
    int f = *isf32;
    if (i < NX) { xb[i] = f2bf(loadf(x, i, f)); return; }
    i -= NX;
    if (i < NW1) {
        int r = i / HID1, c = i % HID1;
        W1t[(size_t)c * IN_DIM + r] = f2bf(loadf(W1, i, f));
        return;
    }
    i -= NW1;
    if (i < NW2) {
        int r = i / EMB, c = i % EMB;
        W2t[(size_t)c * HID1 + r] = f2bf(loadf(W2, i, f));
    }
}

// ---------------- m97-style MFMA GEMM: C[Mpad,N] = A[Mpad,K] * Bt[N,K]^T ----------------
template<bool OUTBF16>
__global__ __launch_bounds__(256) void gemm_tile(
    const unsigned short* __restrict__ A,
    const unsigned short* __restrict__ Bt,
    void* __restrict__ Cv,
    int N, int K)
{
    __shared__ unsigned short As[128 * 32];
    __shared__ unsigned short Bs[128 * 32];
    int t = threadIdx.x;
    int wave = t >> 6;
    int lane = t & 63;
    int quad = lane >> 4;
    int l16  = lane & 15;
    int mq = wave & 1, nq = wave >> 1;
    size_t mblk = (size_t)blockIdx.x * 128;
    size_t nblk = (size_t)blockIdx.y * 128;

    floatx4 acc[4][4];
    #pragma unroll
    for (int i = 0; i < 4; ++i)
        #pragma unroll
        for (int j = 0; j < 4; ++j)
            acc[i][j] = (floatx4){0.f, 0.f, 0.f, 0.f};

    const unsigned short* Abase = A + mblk * K;
    const unsigned short* Bbase = Bt + nblk * K;

    for (int kk = 0; kk < K; kk += 32) {
        __syncthreads();
        #pragma unroll
        for (int j = 0; j < 2; ++j) {
            int chunk = (wave << 7) + (j << 6) + lane;
            int r  = chunk >> 2;
            int cs = (chunk & 3) ^ (r & 3);
            const unsigned short* ga = Abase + (size_t)r * K + kk + cs * 8;
            const unsigned short* gb = Bbase + (size_t)r * K + kk + cs * 8;
            __builtin_amdgcn_global_load_lds(
                (const __attribute__((address_space(1))) void*)ga,
                (__attribute__((address_space(3))) void*)(As + (size_t)((wave << 7) + (j << 6)) * 8),
                16, 0, 0);
            __builtin_amdgcn_global_load_lds(
                (const __attribute__((address_space(1))) void*)gb,
                (__attribute__((address_space(3))) void*)(Bs + (size_t)((wave << 7) + (j << 6)) * 8),
                16, 0, 0);
        }
        __syncthreads();

        short8 af[4], bf[4];
        #pragma unroll
        for (int i = 0; i < 4; ++i) {
            int ar = mq * 64 + i * 16 + l16;
            int br = nq * 64 + i * 16 + l16;
            af[i] = *(const short8*)(const void*)(As + ar * 32 + (quad ^ (ar & 3)) * 8);
            bf[i] = *(const short8*)(const void*)(Bs + br * 32 + (quad ^ (br & 3)) * 8);
        }
        #pragma unroll
        for (int i = 0; i < 4; ++i)
            #pragma unroll
            for (int j = 0; j < 4; ++j)
                acc[i][j] = __builtin_amdgcn_mfma_f32_16x16x32_bf16(af[i], bf[j], acc[i][j], 0, 0, 0);
    }

    size_t crow0 = mblk + mq * 64 + quad * 4;
    size_t ccol0 = nblk + nq * 64 + l16;
    #pragma unroll
    for (int i = 0; i < 4; ++i) {
        #pragma unroll
        for (int r = 0; r < 4; ++r) {
            size_t row = crow0 + i * 16 + r;
            size_t b = row * N + ccol0;
            #pragma unroll
            for (int j = 0; j < 4; ++j) {
                if (OUTBF16) ((unsigned short*)Cv)[b + j * 16] = f2bf(acc[i][j][r]);
                else         ((float*)Cv)[b + j * 16] = acc[i][j][r];
            }
        }
    }
}

// ---------------- alpha for layer 1 (bf16 h1): as1/ad1 [N,8] ----------------
__global__ __launch_bounds__(256) void alpha1_kernel(
    const unsigned short* __restrict__ h1,
    const void* __restrict__ a_src, const void* __restrict__ a_dst,
    const int* __restrict__ isf32,
    float* __restrict__ as1, float* __restrict__ ad1)
{
    int n = blockIdx.x, t = threadIdx.x;
    int f = *isf32;
    ushort4v hv = *(const ushort4v*)(const void*)(h1 + (size_t)n * HID1 + t * 4);
    float ps = 0.f, pd = 0.f;
    #pragma unroll
    for (int i = 0; i < 4; ++i) {
        float h = bf2f(hv[i]);
        ps += h * loadf(a_src, t * 4 + i, f);
        pd += h * loadf(a_dst, t * 4 + i, f);
    }
    #pragma unroll
    for (int off = 1; off < 32; off <<= 1) {
        ps += __shfl_xor(ps, off, 64);
        pd += __shfl_xor(pd, off, 64);
    }
    if ((t & 31) == 0) {
        int h = t >> 5;
        as1[n * 8 + h] = ps;
        ad1[n * 8 + h] = pd;
    }
}

// ---------------- edge-weight precompute, layer 1: ew1[h][e], den1[n,h] via atomics ----------------
// Removes the per-lane-redundant as1-gather + lrelu + exp from agg1 (was 21.8M lane-exps;
// now 1.36M total). Gathers hit the L2-resident 320KB as1/ad1 tables.
__global__ __launch_bounds__(256) void ew1_kernel(
    const int* __restrict__ csr_src, const int* __restrict__ csr_dst,
    const float* __restrict__ as1, const float* __restrict__ ad1,
    float* __restrict__ ew1, float* __restrict__ den1)
{
    int e = blockIdx.x * 256 + threadIdx.x;
    if (e >= ETOT) return;
    int h = blockIdx.y;
    int s = csr_src[e]; s &= 0x7fffffff; if (s >= NN) s = 0;
    int d = csr_dst[e]; d &= 0x7fffffff; if (d >= NN) d = 0;
    float w = __expf(lrelu(as1[s * 8 + h] + ad1[d * 8 + h]));
    ew1[(size_t)h * EPAD + e] = w;
    atomicAdd(&den1[d * 8 + h], w);
}

// ---------------- layer-1 SpMM aggregate + ELU, HEAD-PARTITIONED (L2-resident slices) ----------------
// block = (node-group, head); head = blockIdx&7 -> XCD pinning (R6: fetch 147MB->15.7MB).
// Wave per (node, head); 8 eighth-groups x 8 lanes x 16 cols/lane (2x dwordx4 per edge).
// Weights preloaded (ew1) and denominators precomputed (den1): inner loop is pure gather-FMA.
__global__ __launch_bounds__(256) void agg1_kernel(
    const unsigned short* __restrict__ h1, const int* __restrict__ offsets,
    const int* __restrict__ csr_src, const float* __restrict__ ew1,
    const float* __restrict__ den1, const void* __restrict__ b1,
    const int* __restrict__ isf32,
    unsigned short* __restrict__ hmid)
{
    int head = blockIdx.x & 7;
    int ng   = blockIdx.x >> 3;
    int n    = ng * 4 + (threadIdx.x >> 6);
    if (n >= NN) return;
    int lane = threadIdx.x & 63;
    int oc   = lane >> 3;      // eighth-group 0..7 (edge partition)
    int sl   = lane & 7;       // col slot: 16 cols = 32B at head*256B + sl*32B
    int f = *isf32;
    int beg = offsets[n], end = offsets[n + 1];
    if (beg < 0) beg = 0; if (end > ETOT) end = ETOT;
    const unsigned* rb = (const unsigned*)h1 + head * 64 + sl * 8;   // + s*512 (u32 units)
    const float* ewh = ew1 + (size_t)head * EPAD;

    float acc[16];
    #pragma unroll
    for (int j = 0; j < 16; ++j) acc[j] = 0.f;

    int i = beg + oc;
    // 4 edges in flight per eighth (stride 32)
    for (; i + 24 < end; i += 32) {
        int s0 = csr_src[i];      s0 &= 0x7fffffff; if (s0 >= NN) s0 = 0;
        int s1 = csr_src[i + 8];  s1 &= 0x7fffffff; if (s1 >= NN) s1 = 0;
        int s2 = csr_src[i + 16]; s2 &= 0x7fffffff; if (s2 >= NN) s2 = 0;
        int s3 = csr_src[i + 24]; s3 &= 0x7fffffff; if (s3 >= NN) s3 = 0;
        uint4v a0 = *(const uint4v*)(const void*)(rb + (size_t)s0 * 512);
        uint4v c0v = *(const uint4v*)(const void*)(rb + (size_t)s0 * 512 + 4);
        uint4v a1 = *(const uint4v*)(const void*)(rb + (size_t)s1 * 512);
        uint4v c1v = *(const uint4v*)(const void*)(rb + (size_t)s1 * 512 + 4);
        uint4v a2 = *(const uint4v*)(const void*)(rb + (size_t)s2 * 512);
        uint4v c2v = *(const uint4v*)(const void*)(rb + (size_t)s2 * 512 + 4);
        uint4v a3 = *(const uint4v*)(const void*)(rb + (size_t)s3 * 512);
        uint4v c3v = *(const uint4v*)(const void*)(rb + (size_t)s3 * 512 + 4);
        float w0 = ewh[i], w1 = ewh[i + 8], w2 = ewh[i + 16], w3 = ewh[i + 24];
        #pragma unroll
        for (int k = 0; k < 4; ++k) {
            acc[2 * k]      += (bflo(a0[k]) * w0 + bflo(a1[k]) * w1) + (bflo(a2[k]) * w2 + bflo(a3[k]) * w3);
            acc[2 * k + 1]  += (bfhi(a0[k]) * w0 + bfhi(a1[k]) * w1) + (bfhi(a2[k]) * w2 + bfhi(a3[k]) * w3);
            acc[8 + 2 * k]  += (bflo(c0v[k]) * w0 + bflo(c1v[k]) * w1) + (bflo(c2v[k]) * w2 + bflo(c3v[k]) * w3);
            acc[9 + 2 * k]  += (bfhi(c0v[k]) * w0 + bfhi(c1v[k]) * w1) + (bfhi(c2v[k]) * w2 + bfhi(c3v[k]) * w3);
        }
    }
    // 2 edges in flight
    for (; i + 8 < end; i += 16) {
        int s0 = csr_src[i];     s0 &= 0x7fffffff; if (s0 >= NN) s0 = 0;
        int s1 = csr_src[i + 8]; s1 &= 0x7fffffff; if (s1 >= NN) s1 = 0;
        uint4v a0 = *(const uint4v*)(const void*)(rb + (size_t)s0 * 512);
        uint4v c0v = *(const uint4v*)(const void*)(rb + (size_t)s0 * 512 + 4);
        uint4v a1 = *(const uint4v*)(const void*)(rb + (size_t)s1 * 512);
        uint4v c1v = *(const uint4v*)(const void*)(rb + (size_t)s1 * 512 + 4);
        float w0 = ewh[i], w1 = ewh[i + 8];
        #pragma unroll
        for (int k = 0; k < 4; ++k) {
            acc[2 * k]      += bflo(a0[k]) * w0 + bflo(a1[k]) * w1;
            acc[2 * k + 1]  += bfhi(a0[k]) * w0 + bfhi(a1[k]) * w1;
            acc[8 + 2 * k]  += bflo(c0v[k]) * w0 + bflo(c1v[k]) * w1;
            acc[9 + 2 * k]  += bfhi(c0v[k]) * w0 + bfhi(c1v[k]) * w1;
        }
    }
    // tail (at most one edge per eighth remains)
    if (i < end) {
        int s0 = csr_src[i]; s0 &= 0x7fffffff; if (s0 >= NN) s0 = 0;
        uint4v a0 = *(const uint4v*)(const void*)(rb + (size_t)s0 * 512);
        uint4v c0v = *(const uint4v*)(const void*)(rb + (size_t)s0 * 512 + 4);
        float w0 = ewh[i];
        #pragma unroll
        for (int k = 0; k < 4; ++k) {
            acc[2 * k]      += bflo(a0[k]) * w0;
            acc[2 * k + 1]  += bfhi(a0[k]) * w0;
            acc[8 + 2 * k]  += bflo(c0v[k]) * w0;
            acc[9 + 2 * k]  += bfhi(c0v[k]) * w0;
        }
    }

    // combine the 8 eighth-groups in-register
    #pragma unroll
    for (int j = 0; j < 16; ++j) {
        acc[j] += __shfl_xor(acc[j], 8, 64);
        acc[j] += __shfl_xor(acc[j], 16, 64);
        acc[j] += __shfl_xor(acc[j], 32, 64);
    }

    if (oc == 0) {
        float rden = 1.0f / fmaxf(den1[n * 8 + head], 1e-30f);
        int c0 = head * 128 + sl * 16;
        uint4v oA, oB;
        #pragma unroll
        for (int k = 0; k < 4; ++k) {
            float v0 = acc[2 * k]     * rden + loadf(b1, c0 + 2 * k, f);
            float v1 = acc[2 * k + 1] * rden + loadf(b1, c0 + 2 * k + 1, f);
            v0 = v0 > 0.f ? v0 : (__expf(v0) - 1.0f);   // ELU
            v1 = v1 > 0.f ? v1 : (__expf(v1) - 1.0f);
            oA[k] = packbf(v0, v1);
            float u0 = acc[8 + 2 * k] * rden + loadf(b1, c0 + 8 + 2 * k, f);
            float u1 = acc[9 + 2 * k] * rden + loadf(b1, c0 + 9 + 2 * k, f);
            u0 = u0 > 0.f ? u0 : (__expf(u0) - 1.0f);
            u1 = u1 > 0.f ? u1 : (__expf(u1) - 1.0f);
            oB[k] = packbf(u0, u1);
        }
        unsigned* hw = (unsigned*)hmid;
        *(uint4v*)(void*)(hw + (size_t)n * 512 + head * 64 + sl * 8)     = oA;
        *(uint4v*)(void*)(hw + (size_t)n * 512 + head * 64 + sl * 8 + 4) = oB;
    }
}

// ---------------- alpha for layer 2 (bf16 h2): as2/ad2 [N] ----------------
__global__ __launch_bounds__(256) void alpha2_kernel(
    const unsigned short* __restrict__ h2,
    const void* __restrict__ a_src2, const void* __restrict__ a_dst2,
    const int* __restrict__ isf32,
    float* __restrict__ as2, float* __restrict__ ad2)
{
    int n = blockIdx.x, t = threadIdx.x;
    int f = *isf32;
    float v = bf2f(h2[(size_t)n * EMB + t]);
    float ps = v * loadf(a_src2, t, f);
    float pd = v * loadf(a_dst2, t, f);
    __shared__ float rs[256], rdm[256];
    rs[t] = ps; rdm[t] = pd;
    __syncthreads();
    for (int off = 128; off > 0; off >>= 1) {
        if (t < off) { rs[t] += rs[t + off]; rdm[t] += rdm[t + off]; }
        __syncthreads();
    }
    if (t == 0) { as2[n] = rs[0]; ad2[n] = rdm[0]; }
}

// ---------------- edge-weight precompute, layer 2: ew2[e], den2[n] ----------------
__global__ __launch_bounds__(256) void ew2_kernel(
    const int* __restrict__ csr_src, const int* __restrict__ csr_dst,
    const float* __restrict__ as2, const float* __restrict__ ad2,
    float* __restrict__ ew2, float* __restrict__ den2)
{
    int e = blockIdx.x * 256 + threadIdx.x;
    if (e >= ETOT) return;
    int s = csr_src[e]; s &= 0x7fffffff; if (s >= NN) s = 0;
    int d = csr_dst[e]; d &= 0x7fffffff; if (d >= NN) d = 0;
    float w = __expf(lrelu(as2[s] + ad2[d]));
    ew2[e] = w;
    atomicAdd(&den2[d], w);
}

// ---------------- layer-2 SpMM aggregate, COLUMN-CHUNK-PARTITIONED ----------------
// block = (node-group, chunk); chunk = blockIdx&3. Per-XCD slice = 1.28MB < 4MB L2.
// 8 eighth-groups x 8 lanes x 8 cols/lane (one dwordx4/edge); ew2/den2 precomputed.
__global__ __launch_bounds__(256) void agg2_kernel(
    const unsigned short* __restrict__ h2, const int* __restrict__ offsets,
    const int* __restrict__ csr_src, const float* __restrict__ ew2,
    const float* __restrict__ den2, const void* __restrict__ b2,
    const int* __restrict__ isf32,
    float* __restrict__ out)
{
    int chunk = blockIdx.x & 3;
    int ng    = blockIdx.x >> 2;
    int n     = ng * 4 + (threadIdx.x >> 6);
    if (n >= NN) return;
    int lane = threadIdx.x & 63;
    int oc   = lane >> 3;      // eighth-group 0..7
    int sl   = lane & 7;       // 8 cols: chunk*64 + sl*8 ..
    int f = *isf32;
    int beg = offsets[n], end = offsets[n + 1];
    if (beg < 0) beg = 0; if (end > ETOT) end = ETOT;
    const unsigned* rb = (const unsigned*)h2 + chunk * 32 + sl * 4;  // + s*128 (u32 units)

    float acc[8];
    #pragma unroll
    for (int j = 0; j < 8; ++j) acc[j] = 0.f;

    int i = beg + oc;
    for (; i + 24 < end; i += 32) {
        int s0 = csr_src[i];      s0 &= 0x7fffffff; if (s0 >= NN) s0 = 0;
        int s1 = csr_src[i + 8];  s1 &= 0x7fffffff; if (s1 >= NN) s1 = 0;
        int s2 = csr_src[i + 16]; s2 &= 0x7fffffff; if (s2 >= NN) s2 = 0;
        int s3 = csr_src[i + 24]; s3 &= 0x7fffffff; if (s3 >= NN) s3 = 0;
        uint4v v0 = *(const uint4v*)(const void*)(rb + (size_t)s0 * 128);
        uint4v v1 = *(const uint4v*)(const void*)(rb + (size_t)s1 * 128);
        uint4v v2 = *(const uint4v*)(const void*)(rb + (size_t)s2 * 128);
        uint4v v3 = *(const uint4v*)(const void*)(rb + (size_t)s3 * 128);
        float w0 = ew2[i], w1 = ew2[i + 8], w2 = ew2[i + 16], w3 = ew2[i + 24];
        #pragma unroll
        for (int k = 0; k < 4; ++k) {
            acc[2 * k]     += (bflo(v0[k]) * w0 + bflo(v1[k]) * w1) + (bflo(v2[k]) * w2 + bflo(v3[k]) * w3);
            acc[2 * k + 1] += (bfhi(v0[k]) * w0 + bfhi(v1[k]) * w1) + (bfhi(v2[k]) * w2 + bfhi(v3[k]) * w3);
        }
    }
    for (; i + 8 < end; i += 16) {
        int s0 = csr_src[i];     s0 &= 0x7fffffff; if (s0 >= NN) s0 = 0;
        int s1 = csr_src[i + 8]; s1 &= 0x7fffffff; if (s1 >= NN) s1 = 0;
        uint4v v0 = *(const uint4v*)(const void*)(rb + (size_t)s0 * 128);
        uint4v v1 = *(const uint4v*)(const void*)(rb + (size_t)s1 * 128);
        float w0 = ew2[i], w1 = ew2[i + 8];
        #pragma unroll
        for (int k = 0; k < 4; ++k) {
            acc[2 * k]     += bflo(v0[k]) * w0 + bflo(v1[k]) * w1;
            acc[2 * k + 1] += bfhi(v0[k]) * w0 + bfhi(v1[k]) * w1;
        }
    }
    if (i < end) {
        int s0 = csr_src[i]; s0 &= 0x7fffffff; if (s0 >= NN) s0 = 0;
        uint4v v0 = *(const uint4v*)(const void*)(rb + (size_t)s0 * 128);
        float w0 = ew2[i];
        #pragma unroll
        for (int k = 0; k < 4; ++k) {
            acc[2 * k]     += bflo(v0[k]) * w0;
            acc[2 * k + 1] += bfhi(v0[k]) * w0;
        }
    }

    #pragma unroll
    for (int j = 0; j < 8; ++j) {
        acc[j] += __shfl_xor(acc[j], 8, 64);
        acc[j] += __shfl_xor(acc[j], 16, 64);
        acc[j] += __shfl_xor(acc[j], 32, 64);
    }

    if (oc == 0) {
        float rden = 1.0f / fmaxf(den2[n], 1e-30f);
        int c0 = chunk * 64 + sl * 8;
        floatx4 o0, o1;
        #pragma unroll
        for (int j = 0; j < 4; ++j) {
            o0[j] = acc[j]     * rden + loadf(b2, c0 + j, f);
            o1[j] = acc[4 + j] * rden + loadf(b2, c0 + 4 + j, f);
        }
        *(floatx4*)(void*)(out + (size_t)n * EMB + c0)     = o0;
        *(floatx4*)(void*)(out + (size_t)n * EMB + c0 + 4) = o1;
    }
}

extern "C" void kernel_launch(void* const* d_in, const int* in_sizes, int n_in,
                              void* d_out, int out_size, void* d_ws, size_t ws_size,
                              hipStream_t stream)
{
    const void* x      = d_in[0];
    const void* edge   = d_in[1];
    const void* W1     = d_in[2];
    const void* a_src1 = d_in[3];
    const void* a_dst1 = d_in[4];
    const void* b1     = d_in[5];
    const void* W2     = d_in[6];
    const void* a_src2 = d_in[7];
    const void* a_dst2 = d_in[8];
    const void* b2     = d_in[9];
    float* out = (float*)d_out;

    char* ws = (char*)d_ws;
    size_t off = 0;
    auto alloc = [&](size_t bytes) -> void* {
        void* p = ws + off;
        off += (bytes + 255) & ~(size_t)255;
        return p;
    };
    // zero-span: counts .. den2 are contiguous (256B-aligned chunks); zeroed in one launch
    int*            counts = (int*)alloc((NN + 2) * 4);   // counts[NN]=eflag, counts[NN+1]=isf32
    float*          den1   = (float*)alloc((size_t)NN * 8 * 4);
    float*          den2   = (float*)alloc((size_t)NN * 4);
    int             zspan  = (int)(((char*)den2 - (char*)counts) / 4) + NN;
    int*            offs   = (int*)alloc((NN + 1) * 4);
    int*            cursor = (int*)alloc(NN * 4);
    int*            csr    = (int*)alloc((size_t)ETOT * 4);
    int*            csrd   = (int*)alloc((size_t)ETOT * 4);
    float*          as1    = (float*)alloc((size_t)NN * 8 * 4);
    float*          ad1    = (float*)alloc((size_t)NN * 8 * 4);
    float*          as2    = (float*)alloc((size_t)NN * 4);
    float*          ad2    = (float*)alloc((size_t)NN * 4);
    float*          ew1    = (float*)alloc((size_t)8 * EPAD * 4);
    float*          ew2    = (float*)alloc((size_t)EPAD * 4);
    unsigned short* xb     = (unsigned short*)alloc((size_t)MPAD * IN_DIM * 2);
    unsigned short* W1t    = (unsigned short*)alloc((size_t)IN_DIM * HID1 * 2);
    unsigned short* W2t    = (unsigned short*)alloc((size_t)HID1 * EMB * 2);
    unsigned short* h1b    = (unsigned short*)alloc((size_t)MPAD * HID1 * 2);
    unsigned short* hmid   = (unsigned short*)alloc((size_t)MPAD * HID1 * 2);
    unsigned short* h2b    = (unsigned short*)alloc((size_t)MPAD * EMB * 2);
    int* eflag = counts + NN;
    int* isf32 = counts + NN + 1;

    zero_kernel<<<(zspan + 255) / 256, 256, 0, stream>>>(counts, zspan);
    probe_kernel<<<DETB + 1, 256, 0, stream>>>((const int*)edge, (const unsigned*)x, eflag, isf32);

    count_kernel<<<(E0 + 255) / 256, 256, 0, stream>>>(edge, eflag, counts);
    scan_kernel<<<1, 1024, 0, stream>>>(counts, offs, cursor);
    scatter_kernel<<<(ETOT + 255) / 256, 256, 0, stream>>>(edge, eflag, cursor, csr, csrd);

    // fused bf16 conversions: x row-major; W1,W2 transposed to [N][K]
    convall_kernel<<<(NX + NW1 + NW2 + 255) / 256, 256, 0, stream>>>(
        x, W1, W2, xb, W1t, W2t, isf32);

    // layer 1 GEMM (m97-style MFMA): h1b (bf16) = x @ W1
    dim3 g1(MPAD / 128, HID1 / 128);
    gemm_tile<true><<<g1, 256, 0, stream>>>(xb, W1t, h1b, HID1, IN_DIM);

    alpha1_kernel<<<NN, 256, 0, stream>>>(h1b, a_src1, a_dst1, isf32, as1, ad1);
    dim3 ge1((ETOT + 255) / 256, 8);
    ew1_kernel<<<ge1, 256, 0, stream>>>(csr, csrd, as1, ad1, ew1, den1);
    // head-partitioned: 2500 node-groups x 8 heads; head = bid & 7 -> XCD pinning
    agg1_kernel<<<(NN / 4) * 8, 256, 0, stream>>>(h1b, offs, csr, ew1, den1, b1, isf32, hmid);

    // layer 2 GEMM (m97-style MFMA): h2b (bf16) = hmid @ W2
    dim3 g2(MPAD / 128, EMB / 128);
    gemm_tile<true><<<g2, 256, 0, stream>>>(hmid, W2t, h2b, EMB, HID1);

    alpha2_kernel<<<NN, 256, 0, stream>>>(h2b, a_src2, a_dst2, isf32, as2, ad2);
    ew2_kernel<<<(ETOT + 255) / 256, 256, 0, stream>>>(csr, csrd, as2, ad2, ew2, den2);
    // chunk-partitioned: 2500 node-groups x 4 col-chunks
    agg2_kernel<<<(NN / 4) * 4, 256, 0, stream>>>(h2b, offs, csr, ew2, den2, b2, isf32, out);
}

// Round 8
// 264.861 us; speedup vs baseline: 1.6247x; 1.6247x over previous
//
#include <hip/hip_runtime.h>
#include <hip/hip_bf16.h>

typedef __attribute__((ext_vector_type(8))) short short8;
typedef __attribute__((ext_vector_type(4))) float floatx4;
typedef __attribute__((ext_vector_type(4))) unsigned short ushort4v;
typedef __attribute__((ext_vector_type(8))) unsigned short ushort8v;
typedef __attribute__((ext_vector_type(2))) unsigned int uint2v;
typedef __attribute__((ext_vector_type(4))) unsigned int uint4v;

#define NN 10000
#define E0 160000
#define ETOT (E0 + NN)
#define IN_DIM 512
#define HID1 1024   /* HEADS*HID = 8*128 */
#define EMB 256
#define MPAD 10112  /* 79 * 128 */
#define NX (NN * IN_DIM)
#define NW1 (IN_DIM * HID1)
#define NW2 (HID1 * EMB)

__device__ __forceinline__ float bf2f(unsigned short u) {
    unsigned v = ((unsigned)u) << 16;
    float f;
    __builtin_memcpy(&f, &v, 4);
    return f;
}
__device__ __forceinline__ float bflo(unsigned v) {
    unsigned x = v << 16;
    float f; __builtin_memcpy(&f, &x, 4);
    return f;
}
__device__ __forceinline__ float bfhi(unsigned v) {
    unsigned x = v & 0xffff0000u;
    float f; __builtin_memcpy(&f, &x, 4);
    return f;
}
__device__ __forceinline__ unsigned short f2bf(float f) {
    unsigned u;
    __builtin_memcpy(&u, &f, 4);
    unsigned lsb = (u >> 16) & 1;
    u += 0x7fff + lsb;           // round-to-nearest-even
    return (unsigned short)(u >> 16);
}
__device__ __forceinline__ float loadf(const void* p, size_t i, int isf32) {
    if (isf32) return ((const float*)p)[i];
    return bf2f(((const unsigned short*)p)[i]);
}
__device__ __forceinline__ float lrelu(float e) { return e > 0.f ? e : 0.2f * e; }

// ---------------- fused zero + dtype probes ----------------
// blocks 0..zb-1 zero the [counts..ad2] span. Block 0 additionally does the edge-dtype
// probe (16K odd-word samples, deterministic single-block -> no init race on eflag);
// block 1 does the float-dtype probe. eflag/isf32 live OUTSIDE the zero span.
__global__ __launch_bounds__(256) void probezero_kernel(
    const int* __restrict__ ei32, const unsigned* __restrict__ xw,
    int* __restrict__ zbase, int zn, int* __restrict__ eflag, int* __restrict__ isf32)
{
    int b = blockIdx.x, t = threadIdx.x;
    int i = b * 256 + t;
    if (i < zn) zbase[i] = 0;
    if (b == 0) {
        // int64 edges: odd words are high halves of src ids -> all 0.
        // int32 edges: odd words are node ids -> nonzero w.h.p. (16384 samples).
        int any = 0;
        #pragma unroll
        for (int k = 0; k < 64; ++k) {
            int idx = (t + k * 256) * 2 + 1;   // < 32768*2 < 2*E0
            any |= ei32[idx];
        }
        __shared__ int sf;
        if (t == 0) sf = 0;
        __syncthreads();
        if (any) atomicOr(&sf, 1);
        __syncthreads();
        if (t == 0) *eflag = sf;
    } else if (b == 1) {
        __shared__ int cnt[256];
        int c = 0;
        #pragma unroll
        for (int j = 0; j < 16; ++j) {
            unsigned w = xw[t * 16 + j];
            int ex = (w >> 7) & 0xFF;
            if (ex >= 110 && ex <= 135) c++;
        }
        cnt[t] = c;
        __syncthreads();
        for (int off = 128; off > 0; off >>= 1) {
            if (t < off) cnt[t] += cnt[t + off];
            __syncthreads();
        }
        if (t == 0) *isf32 = (cnt[0] < 2048) ? 1 : 0;
    }
}

__device__ __forceinline__ int load_edge(const void* ei, long long idx, int m32) {
    if (m32) return ((const int*)ei)[idx];
    return (int)(((const long long*)ei)[idx]);
}

// ---------------- CSR build ----------------
__global__ void count_kernel(const void* ei, const int* flag, int* counts) {
    int e = blockIdx.x * 256 + threadIdx.x;
    if (e < E0) {
        int m32 = (*flag != 0);
        int d = load_edge(ei, (long long)E0 + e, m32);
        if (d >= 0 && d < NN) atomicAdd(&counts[d], 1);
    }
}

// shfl-based block scan: 1024 threads x 10 values, 2 barriers total.
__global__ __launch_bounds__(1024) void scan_kernel(const int* counts, int* offsets, int* cursor) {
    __shared__ int wsum[16];
    int t = threadIdx.x;
    int lane = t & 63, wv = t >> 6;
    int base = t * 10;
    int local[10];
    int s = 0;
    #pragma unroll
    for (int j = 0; j < 10; ++j) {
        int idx = base + j;
        int v = (idx < NN) ? (counts[idx] + 1) : 0;  // +1 self loop
        local[j] = v; s += v;
    }
    int v = s;
    #pragma unroll
    for (int d = 1; d < 64; d <<= 1) {
        int o = __shfl_up(v, d, 64);
        if (lane >= d) v += o;
    }
    if (lane == 63) wsum[wv] = v;
    __syncthreads();
    if (t < 16) {
        int w = wsum[t];
        #pragma unroll
        for (int d = 1; d < 16; d <<= 1) {
            int o = __shfl_up(w, d, 16);
            if (t >= d) w += o;
        }
        wsum[t] = w;
    }
    __syncthreads();
    int woff = (wv == 0) ? 0 : wsum[wv - 1];
    int run = woff + v - s;
    #pragma unroll
    for (int j = 0; j < 10; ++j) {
        int idx = base + j;
        if (idx < NN) { offsets[idx] = run; cursor[idx] = run; run += local[j]; }
    }
    if (t == 1023) offsets[NN] = wsum[15];
}

__global__ void scatter_kernel(const void* ei, const int* flag, int* cursor, int* csr_src) {
    int e = blockIdx.x * 256 + threadIdx.x;
    if (e >= ETOT) return;
    int m32 = (*flag != 0);
    int s, d;
    if (e < E0) { s = load_edge(ei, e, m32); d = load_edge(ei, (long long)E0 + e, m32); }
    else { s = d = e - E0; }
    if (s < 0) s = 0; if (s >= NN) s = NN - 1;
    if (d < 0) d = 0; if (d >= NN) d = NN - 1;
    int pos = atomicAdd(&cursor[d], 1);
    if (pos >= 0 && pos < ETOT) csr_src[pos] = s;
}

// ---------------- fused fp32->bf16 conversions (x, W1^T, W2^T in one launch) ----------------
__global__ void convall_kernel(const void* x, const void* W1, const void* W2,
                               unsigned short* xb, unsigned short* W1t, unsigned short* W2t,
                               const int* isf32)
{
    int i = blockIdx.x * 256 + threadIdx.x;
    int f = *isf32;
    if (i < NX) { xb[i] = f2bf(loadf(x, i, f)); return; }
    i -= NX;
    if (i < NW1) {
        int r = i / HID1, c = i % HID1;
        W1t[(size_t)c * IN_DIM + r] = f2bf(loadf(W1, i, f));
        return;
    }
    i -= NW1;
    if (i < NW2) {
        int r = i / EMB, c = i % EMB;
        W2t[(size_t)c * HID1 + r] = f2bf(loadf(W2, i, f));
    }
}

// ---------------- m97-style MFMA GEMM with fused alpha epilogue ----------------
// C[Mpad,N] = A[Mpad,K] * Bt[N,K]^T, bf16 out; additionally accumulates
// as_out[row*HN + head] += sum_c C[row][c]*a_src[c] (head = col>>HSHIFT) via
// shfl-reduced partials + one guarded f32 atomicAdd per (row, colblock) —
// low-contention (<=8 adders/slot) and co-resident with GEMM compute.
template<int HSHIFT, int HN>
__global__ __launch_bounds__(256) void gemm_tile(
    const unsigned short* __restrict__ A,
    const unsigned short* __restrict__ Bt,
    void* __restrict__ Cv, int N, int K,
    const void* __restrict__ a_src, const void* __restrict__ a_dst,
    const int* __restrict__ isf32,
    float* __restrict__ as_out, float* __restrict__ ad_out)
{
    __shared__ unsigned short As[128 * 32];
    __shared__ unsigned short Bs[128 * 32];
    int t = threadIdx.x;
    int wave = t >> 6;
    int lane = t & 63;
    int quad = lane >> 4;
    int l16  = lane & 15;
    int mq = wave & 1, nq = wave >> 1;
    size_t mblk = (size_t)blockIdx.x * 128;
    size_t nblk = (size_t)blockIdx.y * 128;

    floatx4 acc[4][4];
    #pragma unroll
    for (int i = 0; i < 4; ++i)
        #pragma unroll
        for (int j = 0; j < 4; ++j)
            acc[i][j] = (floatx4){0.f, 0.f, 0.f, 0.f};

    const unsigned short* Abase = A + mblk * K;
    const unsigned short* Bbase = Bt + nblk * K;

    for (int kk = 0; kk < K; kk += 32) {
        __syncthreads();
        #pragma unroll
        for (int j = 0; j < 2; ++j) {
            int chunk = (wave << 7) + (j << 6) + lane;
            int r  = chunk >> 2;
            int cs = (chunk & 3) ^ (r & 3);
            const unsigned short* ga = Abase + (size_t)r * K + kk + cs * 8;
            const unsigned short* gb = Bbase + (size_t)r * K + kk + cs * 8;
            __builtin_amdgcn_global_load_lds(
                (const __attribute__((address_space(1))) void*)ga,
                (__attribute__((address_space(3))) void*)(As + (size_t)((wave << 7) + (j << 6)) * 8),
                16, 0, 0);
            __builtin_amdgcn_global_load_lds(
                (const __attribute__((address_space(1))) void*)gb,
                (__attribute__((address_space(3))) void*)(Bs + (size_t)((wave << 7) + (j << 6)) * 8),
                16, 0, 0);
        }
        __syncthreads();

        short8 af[4], bf[4];
        #pragma unroll
        for (int i = 0; i < 4; ++i) {
            int ar = mq * 64 + i * 16 + l16;
            int br = nq * 64 + i * 16 + l16;
            af[i] = *(const short8*)(const void*)(As + ar * 32 + (quad ^ (ar & 3)) * 8);
            bf[i] = *(const short8*)(const void*)(Bs + br * 32 + (quad ^ (br & 3)) * 8);
        }
        #pragma unroll
        for (int i = 0; i < 4; ++i)
            #pragma unroll
            for (int j = 0; j < 4; ++j)
                acc[i][j] = __builtin_amdgcn_mfma_f32_16x16x32_bf16(af[i], bf[j], acc[i][j], 0, 0, 0);
    }

    size_t crow0 = mblk + mq * 64 + quad * 4;
    size_t ccol0 = nblk + nq * 64 + l16;
    #pragma unroll
    for (int i = 0; i < 4; ++i) {
        #pragma unroll
        for (int r = 0; r < 4; ++r) {
            size_t row = crow0 + i * 16 + r;
            size_t b = row * N + ccol0;
            #pragma unroll
            for (int j = 0; j < 4; ++j)
                ((unsigned short*)Cv)[b + j * 16] = f2bf(acc[i][j][r]);
        }
    }

    // fused alpha partials (uses pre-rounding f32 acc — closer to ref than bf16 h)
    int f = *isf32;
    float a_s[4], a_d[4];
    #pragma unroll
    for (int j = 0; j < 4; ++j) {
        a_s[j] = loadf(a_src, ccol0 + j * 16, f);
        a_d[j] = loadf(a_dst, ccol0 + j * 16, f);
    }
    int head = (int)((nblk + (size_t)nq * 64) >> HSHIFT);
    #pragma unroll
    for (int i = 0; i < 4; ++i) {
        #pragma unroll
        for (int r = 0; r < 4; ++r) {
            float ps = acc[i][0][r] * a_s[0] + acc[i][1][r] * a_s[1]
                     + acc[i][2][r] * a_s[2] + acc[i][3][r] * a_s[3];
            float pd = acc[i][0][r] * a_d[0] + acc[i][1][r] * a_d[1]
                     + acc[i][2][r] * a_d[2] + acc[i][3][r] * a_d[3];
            #pragma unroll
            for (int off = 1; off < 16; off <<= 1) {
                ps += __shfl_xor(ps, off, 16);
                pd += __shfl_xor(pd, off, 16);
            }
            if (l16 == 0) {
                size_t row = crow0 + i * 16 + r;
                if (row < NN) {
                    atomicAdd(&as_out[row * HN + head], ps);
                    atomicAdd(&ad_out[row * HN + head], pd);
                }
            }
        }
    }
}

// ---------------- layer-1 single-pass softmax-aggregate + ELU -> hmid bf16 ----------------
// R3's proven 49.7us structure: 2 groups x 128 threads, 8 cols/thread, 4-deep edge pipeline.
__global__ __launch_bounds__(256) void agg1_kernel(
    const unsigned short* __restrict__ h1, const int* __restrict__ offsets,
    const int* __restrict__ csr_src, const float* __restrict__ as1,
    const float* __restrict__ ad1, const void* __restrict__ b1,
    const int* __restrict__ isf32,
    unsigned short* __restrict__ hmid)
{
    int n = blockIdx.x, t = threadIdx.x;
    int f = *isf32;
    int beg = offsets[n], end = offsets[n + 1];
    if (beg < 0) beg = 0; if (end > ETOT) end = ETOT;
    int g = t >> 7;          // edge group 0/1
    int u = t & 127;
    int c0 = u * 8;          // 8 cols per thread
    int hc = u >> 4;         // head = c0/128
    float ad = ad1[n * 8 + hc];

    float den = 0.f;
    float acc[8];
    #pragma unroll
    for (int j = 0; j < 8; ++j) acc[j] = 0.f;

    int i = beg + g;
    for (; i + 6 < end; i += 8) {
        int s0 = csr_src[i];     s0 &= 0x7fffffff; if (s0 >= NN) s0 = 0;
        int s1 = csr_src[i + 2]; s1 &= 0x7fffffff; if (s1 >= NN) s1 = 0;
        int s2 = csr_src[i + 4]; s2 &= 0x7fffffff; if (s2 >= NN) s2 = 0;
        int s3 = csr_src[i + 6]; s3 &= 0x7fffffff; if (s3 >= NN) s3 = 0;
        ushort8v hv0 = *(const ushort8v*)(const void*)(h1 + (size_t)s0 * HID1 + c0);
        ushort8v hv1 = *(const ushort8v*)(const void*)(h1 + (size_t)s1 * HID1 + c0);
        ushort8v hv2 = *(const ushort8v*)(const void*)(h1 + (size_t)s2 * HID1 + c0);
        ushort8v hv3 = *(const ushort8v*)(const void*)(h1 + (size_t)s3 * HID1 + c0);
        float e0 = as1[s0 * 8 + hc] + ad;
        float e1 = as1[s1 * 8 + hc] + ad;
        float e2 = as1[s2 * 8 + hc] + ad;
        float e3 = as1[s3 * 8 + hc] + ad;
        e0 = e0 > 0.f ? e0 : 0.2f * e0;
        e1 = e1 > 0.f ? e1 : 0.2f * e1;
        e2 = e2 > 0.f ? e2 : 0.2f * e2;
        e3 = e3 > 0.f ? e3 : 0.2f * e3;
        float w0 = __expf(e0), w1 = __expf(e1), w2 = __expf(e2), w3 = __expf(e3);
        den += (w0 + w1) + (w2 + w3);
        #pragma unroll
        for (int j = 0; j < 8; ++j)
            acc[j] += (bf2f(hv0[j]) * w0 + bf2f(hv1[j]) * w1)
                    + (bf2f(hv2[j]) * w2 + bf2f(hv3[j]) * w3);
    }
    for (; i + 2 < end; i += 4) {
        int s0 = csr_src[i];     s0 &= 0x7fffffff; if (s0 >= NN) s0 = 0;
        int s1 = csr_src[i + 2]; s1 &= 0x7fffffff; if (s1 >= NN) s1 = 0;
        ushort8v hv0 = *(const ushort8v*)(const void*)(h1 + (size_t)s0 * HID1 + c0);
        ushort8v hv1 = *(const ushort8v*)(const void*)(h1 + (size_t)s1 * HID1 + c0);
        float e0 = as1[s0 * 8 + hc] + ad;
        float e1 = as1[s1 * 8 + hc] + ad;
        e0 = e0 > 0.f ? e0 : 0.2f * e0;
        e1 = e1 > 0.f ? e1 : 0.2f * e1;
        float w0 = __expf(e0), w1 = __expf(e1);
        den += w0 + w1;
        #pragma unroll
        for (int j = 0; j < 8; ++j)
            acc[j] += bf2f(hv0[j]) * w0 + bf2f(hv1[j]) * w1;
    }
    if (i < end) {
        int s0 = csr_src[i]; s0 &= 0x7fffffff; if (s0 >= NN) s0 = 0;
        ushort8v hv0 = *(const ushort8v*)(const void*)(h1 + (size_t)s0 * HID1 + c0);
        float e0 = as1[s0 * 8 + hc] + ad;
        e0 = e0 > 0.f ? e0 : 0.2f * e0;
        float w0 = __expf(e0);
        den += w0;
        #pragma unroll
        for (int j = 0; j < 8; ++j) acc[j] += bf2f(hv0[j]) * w0;
    }

    __shared__ float accsh[128][9];
    __shared__ float densh[128];
    if (g == 1) {
        #pragma unroll
        for (int j = 0; j < 8; ++j) accsh[u][j] = acc[j];
        densh[u] = den;
    }
    __syncthreads();
    if (g == 0) {
        den += densh[u];
        float rden = 1.0f / fmaxf(den, 1e-30f);
        ushort8v outw;
        #pragma unroll
        for (int j = 0; j < 8; ++j) {
            float v = (acc[j] + accsh[u][j]) * rden + loadf(b1, c0 + j, f);
            v = v > 0.f ? v : (__expf(v) - 1.0f);   // ELU
            outw[j] = f2bf(v);
        }
        *(ushort8v*)(void*)(hmid + (size_t)n * HID1 + c0) = outw;
    }
}

// ---------------- layer-2 softmax-aggregate, COLUMN-CHUNK-PARTITIONED (R6, ~6us faster) ----------------
__global__ __launch_bounds__(256) void agg2_kernel(
    const unsigned short* __restrict__ h2, const int* __restrict__ offsets,
    const int* __restrict__ csr_src, const float* __restrict__ as2,
    const float* __restrict__ ad2, const void* __restrict__ b2,
    const int* __restrict__ isf32,
    float* __restrict__ out)
{
    int chunk = blockIdx.x & 3;
    int ng    = blockIdx.x >> 2;
    int n     = ng * 4 + (threadIdx.x >> 6);
    if (n >= NN) return;
    int lane = threadIdx.x & 63;
    int q    = lane >> 4;      // edge quarter-group 0..3
    int sl   = lane & 15;      // 4 cols: chunk*64 + sl*4 ..
    int f = *isf32;
    int beg = offsets[n], end = offsets[n + 1];
    if (beg < 0) beg = 0; if (end > ETOT) end = ETOT;
    float adn = ad2[n];
    const unsigned* rb = (const unsigned*)h2 + chunk * 32 + sl * 2;  // + s*128 (u32 units)

    float den = 0.f;
    float acc[4];
    #pragma unroll
    for (int j = 0; j < 4; ++j) acc[j] = 0.f;

    int i = beg + q;
    for (; i + 12 < end; i += 16) {
        int s0 = csr_src[i];      s0 &= 0x7fffffff; if (s0 >= NN) s0 = 0;
        int s1 = csr_src[i + 4];  s1 &= 0x7fffffff; if (s1 >= NN) s1 = 0;
        int s2 = csr_src[i + 8];  s2 &= 0x7fffffff; if (s2 >= NN) s2 = 0;
        int s3 = csr_src[i + 12]; s3 &= 0x7fffffff; if (s3 >= NN) s3 = 0;
        uint2v v0 = *(const uint2v*)(const void*)(rb + (size_t)s0 * 128);
        uint2v v1 = *(const uint2v*)(const void*)(rb + (size_t)s1 * 128);
        uint2v v2 = *(const uint2v*)(const void*)(rb + (size_t)s2 * 128);
        uint2v v3 = *(const uint2v*)(const void*)(rb + (size_t)s3 * 128);
        float w0 = __expf(lrelu(as2[s0] + adn));
        float w1 = __expf(lrelu(as2[s1] + adn));
        float w2 = __expf(lrelu(as2[s2] + adn));
        float w3 = __expf(lrelu(as2[s3] + adn));
        den += (w0 + w1) + (w2 + w3);
        acc[0] += (bflo(v0[0]) * w0 + bflo(v1[0]) * w1) + (bflo(v2[0]) * w2 + bflo(v3[0]) * w3);
        acc[1] += (bfhi(v0[0]) * w0 + bfhi(v1[0]) * w1) + (bfhi(v2[0]) * w2 + bfhi(v3[0]) * w3);
        acc[2] += (bflo(v0[1]) * w0 + bflo(v1[1]) * w1) + (bflo(v2[1]) * w2 + bflo(v3[1]) * w3);
        acc[3] += (bfhi(v0[1]) * w0 + bfhi(v1[1]) * w1) + (bfhi(v2[1]) * w2 + bfhi(v3[1]) * w3);
    }
    for (; i + 4 < end; i += 8) {
        int s0 = csr_src[i];     s0 &= 0x7fffffff; if (s0 >= NN) s0 = 0;
        int s1 = csr_src[i + 4]; s1 &= 0x7fffffff; if (s1 >= NN) s1 = 0;
        uint2v v0 = *(const uint2v*)(const void*)(rb + (size_t)s0 * 128);
        uint2v v1 = *(const uint2v*)(const void*)(rb + (size_t)s1 * 128);
        float w0 = __expf(lrelu(as2[s0] + adn));
        float w1 = __expf(lrelu(as2[s1] + adn));
        den += w0 + w1;
        acc[0] += bflo(v0[0]) * w0 + bflo(v1[0]) * w1;
        acc[1] += bfhi(v0[0]) * w0 + bfhi(v1[0]) * w1;
        acc[2] += bflo(v0[1]) * w0 + bflo(v1[1]) * w1;
        acc[3] += bfhi(v0[1]) * w0 + bfhi(v1[1]) * w1;
    }
    if (i < end) {
        int s0 = csr_src[i]; s0 &= 0x7fffffff; if (s0 >= NN) s0 = 0;
        uint2v v0 = *(const uint2v*)(const void*)(rb + (size_t)s0 * 128);
        float w0 = __expf(lrelu(as2[s0] + adn));
        den += w0;
        acc[0] += bflo(v0[0]) * w0;
        acc[1] += bfhi(v0[0]) * w0;
        acc[2] += bflo(v0[1]) * w0;
        acc[3] += bfhi(v0[1]) * w0;
    }

    #pragma unroll
    for (int j = 0; j < 4; ++j) {
        acc[j] += __shfl_xor(acc[j], 16, 64);
        acc[j] += __shfl_xor(acc[j], 32, 64);
    }
    den += __shfl_xor(den, 16, 64);
    den += __shfl_xor(den, 32, 64);

    if (q == 0) {
        float rden = 1.0f / fmaxf(den, 1e-30f);
        int c0 = chunk * 64 + sl * 4;
        floatx4 o;
        #pragma unroll
        for (int j = 0; j < 4; ++j)
            o[j] = acc[j] * rden + loadf(b2, c0 + j, f);
        *(floatx4*)(void*)(out + (size_t)n * EMB + c0) = o;
    }
}

extern "C" void kernel_launch(void* const* d_in, const int* in_sizes, int n_in,
                              void* d_out, int out_size, void* d_ws, size_t ws_size,
                              hipStream_t stream)
{
    const void* x      = d_in[0];
    const void* edge   = d_in[1];
    const void* W1     = d_in[2];
    const void* a_src1 = d_in[3];
    const void* a_dst1 = d_in[4];
    const void* b1     = d_in[5];
    const void* W2     = d_in[6];
    const void* a_src2 = d_in[7];
    const void* a_dst2 = d_in[8];
    const void* b2     = d_in[9];
    float* out = (float*)d_out;

    char* ws = (char*)d_ws;
    size_t off = 0;
    auto alloc = [&](size_t bytes) -> void* {
        void* p = ws + off;
        off += (bytes + 255) & ~(size_t)255;
        return p;
    };
    // zero span: counts..ad2 contiguous (zeroed by probezero_kernel)
    int*            counts = (int*)alloc((size_t)NN * 4);
    float*          as1    = (float*)alloc((size_t)NN * 8 * 4);
    float*          ad1    = (float*)alloc((size_t)NN * 8 * 4);
    float*          as2    = (float*)alloc((size_t)NN * 4);
    float*          ad2    = (float*)alloc((size_t)NN * 4);
    int             zn     = (int)(((char*)ad2 - (char*)counts) / 4) + NN;
    int*            flags  = (int*)alloc(2 * 4);          // [0]=eflag [1]=isf32 (NOT zeroed)
    int*            offs   = (int*)alloc((NN + 1) * 4);
    int*            cursor = (int*)alloc(NN * 4);
    int*            csr    = (int*)alloc((size_t)ETOT * 4);
    unsigned short* xb     = (unsigned short*)alloc((size_t)MPAD * IN_DIM * 2);
    unsigned short* W1t    = (unsigned short*)alloc((size_t)IN_DIM * HID1 * 2);
    unsigned short* W2t    = (unsigned short*)alloc((size_t)HID1 * EMB * 2);
    unsigned short* h1b    = (unsigned short*)alloc((size_t)MPAD * HID1 * 2);
    unsigned short* hmid   = (unsigned short*)alloc((size_t)MPAD * HID1 * 2);
    unsigned short* h2b    = (unsigned short*)alloc((size_t)MPAD * EMB * 2);
    int* eflag = flags;
    int* isf32 = flags + 1;

    probezero_kernel<<<(zn + 255) / 256, 256, 0, stream>>>(
        (const int*)edge, (const unsigned*)x, counts, zn, eflag, isf32);

    count_kernel<<<(E0 + 255) / 256, 256, 0, stream>>>(edge, eflag, counts);
    scan_kernel<<<1, 1024, 0, stream>>>(counts, offs, cursor);
    scatter_kernel<<<(ETOT + 255) / 256, 256, 0, stream>>>(edge, eflag, cursor, csr);

    convall_kernel<<<(NX + NW1 + NW2 + 255) / 256, 256, 0, stream>>>(
        x, W1, W2, xb, W1t, W2t, isf32);

    // layer 1 GEMM + fused alpha1: h1b = x @ W1; as1/ad1 accumulated in epilogue
    dim3 g1(MPAD / 128, HID1 / 128);
    gemm_tile<7, 8><<<g1, 256, 0, stream>>>(xb, W1t, h1b, HID1, IN_DIM,
                                            a_src1, a_dst1, isf32, as1, ad1);

    agg1_kernel<<<NN, 256, 0, stream>>>(h1b, offs, csr, as1, ad1, b1, isf32, hmid);

    // layer 2 GEMM + fused alpha2: h2b = hmid @ W2; as2/ad2 accumulated in epilogue
    dim3 g2(MPAD / 128, EMB / 128);
    gemm_tile<8, 1><<<g2, 256, 0, stream>>>(hmid, W2t, h2b, EMB, HID1,
                                            a_src2, a_dst2, isf32, as2, ad2);

    // chunk-partitioned agg2: 2500 node-groups x 4 col-chunks
    agg2_kernel<<<(NN / 4) * 4, 256, 0, stream>>>(h2b, offs, csr, as2, ad2, b2, isf32, out);
}